// Round 1
// baseline (3683.358 us; speedup 1.0000x reference)
//
#include <hip/hip_runtime.h>
#include <hip/hip_bf16.h>

#define N_NODES 100000
#define N_EDGES 600000

// ---------------------------------------------------------------------------
// deg[n] = number of edges with from==n  (== to-degree by reverse-pair symmetry)
__global__ void deg_hist(const int* __restrict__ from, int* __restrict__ deg, int E) {
    int e = blockIdx.x * blockDim.x + threadIdx.x;
    if (e < E) atomicAdd(&deg[from[e]], 1);
}

// ---------------------------------------------------------------------------
// C[M,128] = A[M,64] @ B[64,128] + bias   (node-side GEMM, K=64)
__global__ __launch_bounds__(256) void node_gemm(
    const float* __restrict__ A, const float* __restrict__ B,
    const float* __restrict__ bias, float* __restrict__ C, int M)
{
    __shared__ float As[16][65];
    __shared__ float Bs[16][128];
    int row0 = blockIdx.x * 64;
    int tid = threadIdx.x;
    int tx = tid & 15, ty = tid >> 4;
    float acc[4][8];
    #pragma unroll
    for (int i = 0; i < 4; i++)
        #pragma unroll
        for (int j = 0; j < 8; j++) acc[i][j] = 0.f;

    for (int kk = 0; kk < 64; kk += 16) {
        int m  = tid >> 2;
        int k4 = (tid & 3) * 4;
        float4 v = make_float4(0.f, 0.f, 0.f, 0.f);
        if (row0 + m < M)
            v = *(const float4*)(A + (size_t)(row0 + m) * 64 + kk + k4);
        As[k4 + 0][m] = v.x; As[k4 + 1][m] = v.y;
        As[k4 + 2][m] = v.z; As[k4 + 3][m] = v.w;
        #pragma unroll
        for (int t = 0; t < 2; t++) {
            int id = tid + t * 256;
            int k = id >> 5, n4 = (id & 31) * 4;
            *(float4*)(&Bs[k][n4]) = *(const float4*)(B + (size_t)(kk + k) * 128 + n4);
        }
        __syncthreads();
        #pragma unroll
        for (int k = 0; k < 16; k++) {
            float a[4], b[8];
            #pragma unroll
            for (int i = 0; i < 4; i++) a[i] = As[k][ty * 4 + i];
            #pragma unroll
            for (int j = 0; j < 8; j++) b[j] = Bs[k][tx + j * 16];
            #pragma unroll
            for (int i = 0; i < 4; i++)
                #pragma unroll
                for (int j = 0; j < 8; j++) acc[i][j] += a[i] * b[j];
        }
        __syncthreads();
    }
    #pragma unroll
    for (int i = 0; i < 4; i++) {
        int r = row0 + ty * 4 + i;
        if (r < M) {
            #pragma unroll
            for (int j = 0; j < 8; j++) {
                int c = tx + j * 16;
                C[(size_t)r * 128 + c] = acc[i][j] + bias[c];
            }
        }
    }
}

// ---------------------------------------------------------------------------
// base[e,:] = nodeW1[from[e],:] + ef[e,:16] @ W2[16,128] + (W2_b + W3_b)
__global__ __launch_bounds__(256) void base_kernel(
    const float* __restrict__ nodeW1, const int* __restrict__ from,
    const float* __restrict__ ef, const float* __restrict__ W2,
    const float* __restrict__ W2b, const float* __restrict__ W3b,
    float* __restrict__ base)
{
    __shared__ float efs[2][16];
    int e0 = blockIdx.x * 2;
    int tid = threadIdx.x;
    int sub = tid >> 7, c = tid & 127;
    if (tid < 32)
        efs[tid >> 4][tid & 15] = ef[(size_t)(e0 + (tid >> 4)) * 16 + (tid & 15)];
    __syncthreads();
    int e = e0 + sub;
    float s = W2b[c] + W3b[c];
    #pragma unroll
    for (int k = 0; k < 16; k++) s += efs[sub][k] * W2[k * 128 + c];
    s += nodeW1[(size_t)from[e] * 128 + c];
    base[(size_t)e * 128 + c] = s;
}

// ---------------------------------------------------------------------------
// Edge GEMM:  G[M,128] = act(A[M,128]) @ B[128,128]
//   act = relu if reluA else identity
//   epilogue: optionally store G rows; always atomicAdd row into S[sidx[r],:]
__global__ __launch_bounds__(256) void edge_gemm(
    const float* __restrict__ A, const float* __restrict__ B,
    float* __restrict__ G, float* __restrict__ S,
    const int* __restrict__ sidx, int reluA)
{
    __shared__ float As[16][65];
    __shared__ float Bs[16][128];
    int row0 = blockIdx.x * 64;
    int tid = threadIdx.x;
    int tx = tid & 15, ty = tid >> 4;
    float acc[4][8];
    #pragma unroll
    for (int i = 0; i < 4; i++)
        #pragma unroll
        for (int j = 0; j < 8; j++) acc[i][j] = 0.f;

    for (int kk = 0; kk < 128; kk += 16) {
        int m  = tid >> 2;
        int k4 = (tid & 3) * 4;
        float4 v = *(const float4*)(A + (size_t)(row0 + m) * 128 + kk + k4);
        if (reluA) {
            v.x = fmaxf(v.x, 0.f); v.y = fmaxf(v.y, 0.f);
            v.z = fmaxf(v.z, 0.f); v.w = fmaxf(v.w, 0.f);
        }
        As[k4 + 0][m] = v.x; As[k4 + 1][m] = v.y;
        As[k4 + 2][m] = v.z; As[k4 + 3][m] = v.w;
        #pragma unroll
        for (int t = 0; t < 2; t++) {
            int id = tid + t * 256;
            int k = id >> 5, n4 = (id & 31) * 4;
            *(float4*)(&Bs[k][n4]) = *(const float4*)(B + (size_t)(kk + k) * 128 + n4);
        }
        __syncthreads();
        #pragma unroll
        for (int k = 0; k < 16; k++) {
            float a[4], b[8];
            #pragma unroll
            for (int i = 0; i < 4; i++) a[i] = As[k][ty * 4 + i];
            #pragma unroll
            for (int j = 0; j < 8; j++) b[j] = Bs[k][tx + j * 16];
            #pragma unroll
            for (int i = 0; i < 4; i++)
                #pragma unroll
                for (int j = 0; j < 8; j++) acc[i][j] += a[i] * b[j];
        }
        __syncthreads();
    }
    #pragma unroll
    for (int i = 0; i < 4; i++) {
        int r = row0 + ty * 4 + i;
        int s = sidx[r];
        #pragma unroll
        for (int j = 0; j < 8; j++) {
            int c = tx + j * 16;
            if (G) G[(size_t)r * 128 + c] = acc[i][j];
            atomicAdd(&S[(size_t)s * 128 + c], acc[i][j]);
        }
    }
}

// ---------------------------------------------------------------------------
// h[e,:] = relu(base[e,:] + sW[from[e],:] - g[e^1,:])
__global__ __launch_bounds__(256) void edge_ew(
    const float* __restrict__ base, const float* __restrict__ g,
    const float* __restrict__ sW, const int* __restrict__ from,
    float* __restrict__ h)
{
    int gid = blockIdx.x * 256 + threadIdx.x;   // one float4 per thread
    int e  = gid >> 5;
    int c4 = gid & 31;
    int eb = e ^ 1;
    float4 b  = *(const float4*)(base + (size_t)e  * 128 + c4 * 4);
    float4 gg = *(const float4*)(g    + (size_t)eb * 128 + c4 * 4);
    float4 s  = *(const float4*)(sW   + (size_t)from[e] * 128 + c4 * 4);
    float4 r;
    r.x = fmaxf(b.x + s.x - gg.x, 0.f);
    r.y = fmaxf(b.y + s.y - gg.y, 0.f);
    r.z = fmaxf(b.z + s.z - gg.z, 0.f);
    r.w = fmaxf(b.w + s.w - gg.w, 0.f);
    *(float4*)(h + (size_t)e * 128 + c4 * 4) = r;
}

// ---------------------------------------------------------------------------
// out[n,:] = relu(U1x[n,:] + agg[n,:] + deg[n] * U2_b[:])
__global__ __launch_bounds__(256) void final_out(
    const float* __restrict__ U1x, const float* __restrict__ agg,
    const int* __restrict__ deg, const float* __restrict__ U2b,
    float* __restrict__ out)
{
    int gid = blockIdx.x * 256 + threadIdx.x;   // one float4 per thread
    int n  = gid >> 5;
    if (n >= N_NODES) return;
    int c4 = gid & 31;
    float d = (float)deg[n];
    float4 a  = *(const float4*)(U1x + (size_t)n * 128 + c4 * 4);
    float4 ag = *(const float4*)(agg + (size_t)n * 128 + c4 * 4);
    float4 ub = *(const float4*)(U2b + c4 * 4);
    float4 r;
    r.x = fmaxf(a.x + ag.x + d * ub.x, 0.f);
    r.y = fmaxf(a.y + ag.y + d * ub.y, 0.f);
    r.z = fmaxf(a.z + ag.z + d * ub.z, 0.f);
    r.w = fmaxf(a.w + ag.w + d * ub.w, 0.f);
    *(float4*)(out + (size_t)n * 128 + c4 * 4) = r;
}

// ---------------------------------------------------------------------------
extern "C" void kernel_launch(void* const* d_in, const int* in_sizes, int n_in,
                              void* d_out, int out_size, void* d_ws, size_t ws_size,
                              hipStream_t stream) {
    const float* nf  = (const float*)d_in[0];   // [100000,64]
    const float* ef  = (const float*)d_in[1];   // [600000,16]
    // d_in[2] edge_hiddens: always zeros -> h1 = relu(base), skip first GEMM
    const int* edges = (const int*)d_in[3];     // [2,600000]
    const int* from  = edges;
    const int* to    = edges + N_EDGES;
    const float* W1w = (const float*)d_in[4];
    const float* W1b = (const float*)d_in[5];
    const float* W2w = (const float*)d_in[6];
    const float* W2b = (const float*)d_in[7];
    const float* W3w = (const float*)d_in[8];
    const float* W3b = (const float*)d_in[9];
    const float* U1w = (const float*)d_in[10];
    const float* U1b = (const float*)d_in[11];
    const float* U2w = (const float*)d_in[12];
    const float* U2b = (const float*)d_in[13];
    float* out = (float*)d_out;

    char* w = (char*)d_ws;
    float* nodeW1 = (float*)w; w += (size_t)N_NODES * 128 * 4;  // reused as U1x
    float* sW     = (float*)w; w += (size_t)N_NODES * 128 * 4;  // reused as agg
    float* base   = (float*)w; w += (size_t)N_EDGES * 128 * 4;
    float* h      = (float*)w; w += (size_t)N_EDGES * 128 * 4;
    float* g      = (float*)w; w += (size_t)N_EDGES * 128 * 4;
    int*   deg    = (int*)w;   w += (size_t)N_NODES * 4;

    hipMemsetAsync(deg, 0, (size_t)N_NODES * 4, stream);
    deg_hist<<<(N_EDGES + 255) / 256, 256, 0, stream>>>(from, deg, N_EDGES);

    // loop-invariant precompute
    node_gemm<<<(N_NODES + 63) / 64, 256, 0, stream>>>(nf, W1w, W1b, nodeW1, N_NODES);
    base_kernel<<<N_EDGES / 2, 256, 0, stream>>>(nodeW1, from, ef, W2w, W2b, W3b, base);

    // 6 message-passing steps; step 1 (h1 = relu(base)) folded into first GEMM's A-load
    for (int it = 0; it < 5; ++it) {
        hipMemsetAsync(sW, 0, (size_t)N_NODES * 128 * 4, stream);
        edge_gemm<<<N_EDGES / 64, 256, 0, stream>>>(
            it == 0 ? base : h, W3w, g, sW, from, it == 0 ? 1 : 0);
        edge_ew<<<N_EDGES * 32 / 256, 256, 0, stream>>>(base, g, sW, from, h);
    }

    // readout
    node_gemm<<<(N_NODES + 63) / 64, 256, 0, stream>>>(nf, U1w, U1b, nodeW1, N_NODES);
    hipMemsetAsync(sW, 0, (size_t)N_NODES * 128 * 4, stream);
    edge_gemm<<<N_EDGES / 64, 256, 0, stream>>>(h, U2w, nullptr, sW, to, 0);
    final_out<<<(N_NODES * 32 + 255) / 256, 256, 0, stream>>>(nodeW1, sW, deg, U2b, out);
}

// Round 2
// 2389.913 us; speedup vs baseline: 1.5412x; 1.5412x over previous
//
#include <hip/hip_runtime.h>
#include <hip/hip_bf16.h>

#define N_NODES 100000
#define N_EDGES 600000

typedef __bf16 bf16;
typedef __bf16 bf16x8 __attribute__((ext_vector_type(8)));
typedef float f32x4 __attribute__((ext_vector_type(4)));

// ---------------------------------------------------------------------------
// deg[n] = number of edges with from==n (== to-degree by reverse-pair symmetry)
__global__ void deg_hist(const int* __restrict__ from, int* __restrict__ deg, int E) {
    int e = blockIdx.x * blockDim.x + threadIdx.x;
    if (e < E) atomicAdd(&deg[from[e]], 1);
}

// ---------------------------------------------------------------------------
// C[M,128] = A[M,64] @ B[64,128] + bias   (node-side GEMM, K=64, fp32 vector)
__global__ __launch_bounds__(256) void node_gemm(
    const float* __restrict__ A, const float* __restrict__ B,
    const float* __restrict__ bias, float* __restrict__ C, int M)
{
    __shared__ float As[16][65];
    __shared__ float Bs[16][128];
    int row0 = blockIdx.x * 64;
    int tid = threadIdx.x;
    int tx = tid & 15, ty = tid >> 4;
    float acc[4][8];
    #pragma unroll
    for (int i = 0; i < 4; i++)
        #pragma unroll
        for (int j = 0; j < 8; j++) acc[i][j] = 0.f;

    for (int kk = 0; kk < 64; kk += 16) {
        int m  = tid >> 2;
        int k4 = (tid & 3) * 4;
        float4 v = make_float4(0.f, 0.f, 0.f, 0.f);
        if (row0 + m < M)
            v = *(const float4*)(A + (size_t)(row0 + m) * 64 + kk + k4);
        As[k4 + 0][m] = v.x; As[k4 + 1][m] = v.y;
        As[k4 + 2][m] = v.z; As[k4 + 3][m] = v.w;
        #pragma unroll
        for (int t = 0; t < 2; t++) {
            int id = tid + t * 256;
            int k = id >> 5, n4 = (id & 31) * 4;
            *(float4*)(&Bs[k][n4]) = *(const float4*)(B + (size_t)(kk + k) * 128 + n4);
        }
        __syncthreads();
        #pragma unroll
        for (int k = 0; k < 16; k++) {
            float a[4], b[8];
            #pragma unroll
            for (int i = 0; i < 4; i++) a[i] = As[k][ty * 4 + i];
            #pragma unroll
            for (int j = 0; j < 8; j++) b[j] = Bs[k][tx + j * 16];
            #pragma unroll
            for (int i = 0; i < 4; i++)
                #pragma unroll
                for (int j = 0; j < 8; j++) acc[i][j] += a[i] * b[j];
        }
        __syncthreads();
    }
    #pragma unroll
    for (int i = 0; i < 4; i++) {
        int r = row0 + ty * 4 + i;
        if (r < M) {
            #pragma unroll
            for (int j = 0; j < 8; j++) {
                int c = tx + j * 16;
                C[(size_t)r * 128 + c] = acc[i][j] + bias[c];
            }
        }
    }
}

// ---------------------------------------------------------------------------
// base[e,:] = bf16( nodeW1[from[e],:] + ef[e,:16] @ W2[16,128] + (W2_b + W3_b) )
__global__ __launch_bounds__(256) void base_kernel(
    const float* __restrict__ nodeW1, const int* __restrict__ from,
    const float* __restrict__ ef, const float* __restrict__ W2,
    const float* __restrict__ W2b, const float* __restrict__ W3b,
    bf16* __restrict__ base)
{
    __shared__ float efs[2][16];
    int e0 = blockIdx.x * 2;
    int tid = threadIdx.x;
    int sub = tid >> 7, c = tid & 127;
    if (tid < 32)
        efs[tid >> 4][tid & 15] = ef[(size_t)(e0 + (tid >> 4)) * 16 + (tid & 15)];
    __syncthreads();
    int e = e0 + sub;
    float s = W2b[c] + W3b[c];
    #pragma unroll
    for (int k = 0; k < 16; k++) s += efs[sub][k] * W2[k * 128 + c];
    s += nodeW1[(size_t)from[e] * 128 + c];
    base[(size_t)e * 128 + c] = (bf16)s;
}

// ---------------------------------------------------------------------------
// W3T[n][k] = bf16(W3[k][n]);  U2T[n][k] = bf16(U2[k][n])   (one-time)
__global__ __launch_bounds__(256) void prep_weights(
    const float* __restrict__ W3, const float* __restrict__ U2,
    bf16* __restrict__ W3T, bf16* __restrict__ U2T)
{
    int i = blockIdx.x * 256 + threadIdx.x;
    if (i < 128 * 128) {
        int k = i >> 7, n = i & 127;
        W3T[n * 128 + k] = (bf16)W3[k * 128 + n];
        U2T[n * 128 + k] = (bf16)U2[k * 128 + n];
    }
}

// ---------------------------------------------------------------------------
// Fused edge step GEMM (bf16 MFMA):
//   A[e,:] = fused ? relu(base[e] + sWprev[from[e]] - g[e^1]) : relu(base[e])
//   G      = A @ B   (B given transposed bf16 [n][k])
//   gout[e,:]  = bf16(G[e,:])            (if gout != null)
//   Snext[sidx[e],:] += G[e,:]           (fp32 atomics)
// Tile: 64 edges x 128 cols, K=128. Backlink e^1 is in-tile (row0 is even).
__global__ __launch_bounds__(256) void edge_mfma(
    const bf16* __restrict__ baseB, const bf16* __restrict__ gbuf,
    const float* __restrict__ sWprev, const int* __restrict__ from,
    const bf16* __restrict__ BT,
    bf16* __restrict__ gout, float* __restrict__ Snext,
    const int* __restrict__ sidx, int fused)
{
    __shared__ bf16 As[64][136];    // +8 bf16 pad: row pitch 272B = 17*16B
    __shared__ bf16 Bs[128][136];   // stored [n][k] so B-frag reads are b128
    int row0 = blockIdx.x * 64;
    int tid = threadIdx.x;

    // ---- stage B: whole 128x128 bf16, coalesced 16B chunks ----
    #pragma unroll
    for (int t = 0; t < 8; t++) {
        int cid = tid + t * 256;         // chunk of 8 bf16
        int brow = cid >> 4, bcol = (cid & 15) * 8;
        *(bf16x8*)&Bs[brow][bcol] = *(const bf16x8*)(BT + (size_t)brow * 128 + bcol);
    }

    // ---- stage A: fused h-build, 4 threads/row x 32 cols ----
    int r  = tid >> 2;
    int e  = row0 + r;
    int c0 = (tid & 3) * 32;
    if (!fused) {
        #pragma unroll
        for (int cc = 0; cc < 32; cc += 8) {
            int c = c0 + cc;
            bf16x8 bb = *(const bf16x8*)(baseB + (size_t)e * 128 + c);
            bf16x8 o;
            #pragma unroll
            for (int j = 0; j < 8; j++) o[j] = (bf16)fmaxf((float)bb[j], 0.f);
            *(bf16x8*)&As[r][c] = o;
        }
    } else {
        int fe = from[e];
        const float* sr = sWprev + (size_t)fe * 128;
        const bf16*  gr = gbuf + (size_t)(e ^ 1) * 128;
        #pragma unroll
        for (int cc = 0; cc < 32; cc += 8) {
            int c = c0 + cc;
            bf16x8 bb = *(const bf16x8*)(baseB + (size_t)e * 128 + c);
            bf16x8 gg = *(const bf16x8*)(gr + c);
            float4 s0 = *(const float4*)(sr + c);
            float4 s1 = *(const float4*)(sr + c + 4);
            float sv[8] = {s0.x, s0.y, s0.z, s0.w, s1.x, s1.y, s1.z, s1.w};
            bf16x8 o;
            #pragma unroll
            for (int j = 0; j < 8; j++) {
                float v = (float)bb[j] + sv[j] - (float)gg[j];
                o[j] = (bf16)fmaxf(v, 0.f);
            }
            *(bf16x8*)&As[r][c] = o;
        }
    }
    __syncthreads();

    // ---- MFMA: wave w -> rows [w*16, w*16+16), 8 col-tiles, K=4x32 ----
    int wave = tid >> 6, lane = tid & 63;
    int quad = lane >> 4, mr = lane & 15;
    int m0 = wave * 16;
    f32x4 acc[8];
    #pragma unroll
    for (int n = 0; n < 8; n++) acc[n] = (f32x4){0.f, 0.f, 0.f, 0.f};
    #pragma unroll
    for (int kt = 0; kt < 4; kt++) {
        bf16x8 a = *(const bf16x8*)&As[m0 + mr][kt * 32 + quad * 8];
        #pragma unroll
        for (int n = 0; n < 8; n++) {
            bf16x8 b = *(const bf16x8*)&Bs[n * 16 + mr][kt * 32 + quad * 8];
            acc[n] = __builtin_amdgcn_mfma_f32_16x16x32_bf16(a, b, acc[n], 0, 0, 0);
        }
    }

    // ---- epilogue: C/D layout col=lane&15, row=quad*4+reg ----
    int sr4[4];
    #pragma unroll
    for (int reg = 0; reg < 4; reg++) sr4[reg] = sidx[row0 + m0 + quad * 4 + reg];
    #pragma unroll
    for (int n = 0; n < 8; n++) {
        int col = n * 16 + mr;
        #pragma unroll
        for (int reg = 0; reg < 4; reg++) {
            int rr = row0 + m0 + quad * 4 + reg;
            float v = acc[n][reg];
            if (gout) gout[(size_t)rr * 128 + col] = (bf16)v;
            atomicAdd(Snext + (size_t)sr4[reg] * 128 + col, v);
        }
    }
}

// ---------------------------------------------------------------------------
// out[n,:] = relu(U1x[n,:] + agg[n,:] + deg[n] * U2_b[:])
__global__ __launch_bounds__(256) void final_out(
    const float* __restrict__ U1x, const float* __restrict__ agg,
    const int* __restrict__ deg, const float* __restrict__ U2b,
    float* __restrict__ out)
{
    int gid = blockIdx.x * 256 + threadIdx.x;   // one float4 per thread
    int n  = gid >> 5;
    if (n >= N_NODES) return;
    int c4 = gid & 31;
    float d = (float)deg[n];
    float4 a  = *(const float4*)(U1x + (size_t)n * 128 + c4 * 4);
    float4 ag = *(const float4*)(agg + (size_t)n * 128 + c4 * 4);
    float4 ub = *(const float4*)(U2b + c4 * 4);
    float4 r;
    r.x = fmaxf(a.x + ag.x + d * ub.x, 0.f);
    r.y = fmaxf(a.y + ag.y + d * ub.y, 0.f);
    r.z = fmaxf(a.z + ag.z + d * ub.z, 0.f);
    r.w = fmaxf(a.w + ag.w + d * ub.w, 0.f);
    *(float4*)(out + (size_t)n * 128 + c4 * 4) = r;
}

// ---------------------------------------------------------------------------
extern "C" void kernel_launch(void* const* d_in, const int* in_sizes, int n_in,
                              void* d_out, int out_size, void* d_ws, size_t ws_size,
                              hipStream_t stream) {
    const float* nf  = (const float*)d_in[0];   // [100000,64]
    const float* ef  = (const float*)d_in[1];   // [600000,16]
    // d_in[2] edge_hiddens: zeros -> h1 = relu(base); first GEMM uses fused=0
    const int* edges = (const int*)d_in[3];     // [2,600000]
    const int* from  = edges;
    const int* to    = edges + N_EDGES;
    const float* W1w = (const float*)d_in[4];
    const float* W1b = (const float*)d_in[5];
    const float* W2w = (const float*)d_in[6];
    const float* W2b = (const float*)d_in[7];
    const float* W3w = (const float*)d_in[8];
    const float* W3b = (const float*)d_in[9];
    const float* U1w = (const float*)d_in[10];
    const float* U1b = (const float*)d_in[11];
    const float* U2w = (const float*)d_in[12];
    const float* U2b = (const float*)d_in[13];
    float* out = (float*)d_out;

    const size_t NODE_MAT = (size_t)N_NODES * 128;   // fp32 elems
    const size_t EDGE_MAT = (size_t)N_EDGES * 128;   // bf16 elems
    char* w = (char*)d_ws;
    float* nodeW1 = (float*)w; w += NODE_MAT * 4;        // reused for U1x
    float* S0     = (float*)w; w += NODE_MAT * 4;
    float* S1     = (float*)w; w += NODE_MAT * 4;
    bf16*  baseB  = (bf16*)w;  w += EDGE_MAT * 2;
    bf16*  gbuf   = (bf16*)w;  w += EDGE_MAT * 2;
    bf16*  W3T    = (bf16*)w;  w += 128 * 128 * 2;
    bf16*  U2T    = (bf16*)w;  w += 128 * 128 * 2;
    int*   deg    = (int*)w;   w += (size_t)N_NODES * 4;

    const size_t SBYTES = NODE_MAT * 4;
    float* S[2] = {S0, S1};

    hipMemsetAsync(deg, 0, (size_t)N_NODES * 4, stream);
    deg_hist<<<(N_EDGES + 255) / 256, 256, 0, stream>>>(from, deg, N_EDGES);
    prep_weights<<<(128 * 128 + 255) / 256, 256, 0, stream>>>(W3w, U2w, W3T, U2T);

    node_gemm<<<(N_NODES + 63) / 64, 256, 0, stream>>>(nf, W1w, W1b, nodeW1, N_NODES);
    base_kernel<<<N_EDGES / 2, 256, 0, stream>>>(nodeW1, from, ef, W2w, W2b, W3b, baseB);

    // step 1: h1 = relu(base); produces g1, S1-sums
    hipMemsetAsync(S[0], 0, SBYTES, stream);
    edge_mfma<<<N_EDGES / 64, 256, 0, stream>>>(
        baseB, gbuf, nullptr, from, W3T, gbuf, S[0], from, 0);
    int cur = 0;
    // steps 2..5
    for (int it = 1; it < 5; ++it) {
        hipMemsetAsync(S[cur ^ 1], 0, SBYTES, stream);
        edge_mfma<<<N_EDGES / 64, 256, 0, stream>>>(
            baseB, gbuf, S[cur], from, W3T, gbuf, S[cur ^ 1], from, 1);
        cur ^= 1;
    }
    // readout: h6 built in-flight, B=U2T, scatter by `to`
    hipMemsetAsync(S[cur ^ 1], 0, SBYTES, stream);
    edge_mfma<<<N_EDGES / 64, 256, 0, stream>>>(
        baseB, gbuf, S[cur], from, U2T, nullptr, S[cur ^ 1], to, 1);
    cur ^= 1;

    node_gemm<<<(N_NODES + 63) / 64, 256, 0, stream>>>(nf, U1w, U1b, nodeW1, N_NODES);
    final_out<<<(N_NODES * 32 + 255) / 256, 256, 0, stream>>>(nodeW1, S[cur], deg, U2b, out);
}

// Round 3
// 1776.649 us; speedup vs baseline: 2.0732x; 1.3452x over previous
//
#include <hip/hip_runtime.h>
#include <hip/hip_bf16.h>

#define N_NODES 100000
#define N_EDGES 600000
#define SCAN_BLOCKS ((N_NODES + 255) / 256)   // 391

typedef __bf16 bf16;
typedef __bf16 bf16x2 __attribute__((ext_vector_type(2)));
typedef __bf16 bf16x4 __attribute__((ext_vector_type(4)));
typedef __bf16 bf16x8 __attribute__((ext_vector_type(8)));
typedef float f32x4 __attribute__((ext_vector_type(4)));

// ---------------------------------------------------------------------------
// deg[n] = #edges with from==n (== to-degree by reverse-pair symmetry)
__global__ void deg_hist(const int* __restrict__ from, int* __restrict__ deg, int E) {
    int e = blockIdx.x * blockDim.x + threadIdx.x;
    if (e < E) atomicAdd(&deg[from[e]], 1);
}

// ---- CSR build: per-block sums -> serial scan of partials -> block scan ----
__global__ __launch_bounds__(256) void block_sums(
    const int* __restrict__ deg, int* __restrict__ bsum)
{
    __shared__ int s[256];
    int i = blockIdx.x * 256 + threadIdx.x;
    s[threadIdx.x] = (i < N_NODES) ? deg[i] : 0;
    __syncthreads();
    for (int st = 128; st > 0; st >>= 1) {
        if (threadIdx.x < st) s[threadIdx.x] += s[threadIdx.x + st];
        __syncthreads();
    }
    if (threadIdx.x == 0) bsum[blockIdx.x] = s[0];
}

__global__ __launch_bounds__(256) void scan_partials(
    const int* __restrict__ bsum, int* __restrict__ bpref, int* __restrict__ off)
{
    __shared__ int s[SCAN_BLOCKS];
    for (int i = threadIdx.x; i < SCAN_BLOCKS; i += 256) s[i] = bsum[i];
    __syncthreads();
    if (threadIdx.x == 0) {
        int run = 0;
        for (int i = 0; i < SCAN_BLOCKS; i++) { int t = s[i]; s[i] = run; run += t; }
        off[N_NODES] = run;   // == N_EDGES
    }
    __syncthreads();
    for (int i = threadIdx.x; i < SCAN_BLOCKS; i += 256) bpref[i] = s[i];
}

__global__ __launch_bounds__(256) void block_scan(
    const int* __restrict__ deg, const int* __restrict__ bpref,
    int* __restrict__ off, int* __restrict__ cursor)
{
    __shared__ int s[256];
    int i = blockIdx.x * 256 + threadIdx.x;
    int v = (i < N_NODES) ? deg[i] : 0;
    s[threadIdx.x] = v;
    __syncthreads();
    for (int st = 1; st < 256; st <<= 1) {
        int x = (threadIdx.x >= st) ? s[threadIdx.x - st] : 0;
        __syncthreads();
        s[threadIdx.x] += x;
        __syncthreads();
    }
    if (i < N_NODES) {
        int o = bpref[blockIdx.x] + s[threadIdx.x] - v;   // exclusive
        off[i] = o;
        cursor[i] = o;
    }
}

__global__ void scatter_csr(const int* __restrict__ from, int* __restrict__ cursor,
                            int* __restrict__ se, int E) {
    int e = blockIdx.x * blockDim.x + threadIdx.x;
    if (e < E) {
        int p = atomicAdd(&cursor[from[e]], 1);
        se[p] = e;
    }
}

// ---------------------------------------------------------------------------
// C[M,128] = A[M,64] @ B[64,128] + bias   (node-side GEMM, K=64, fp32 vector)
__global__ __launch_bounds__(256) void node_gemm(
    const float* __restrict__ A, const float* __restrict__ B,
    const float* __restrict__ bias, float* __restrict__ C, int M)
{
    __shared__ float As[16][65];
    __shared__ float Bs[16][128];
    int row0 = blockIdx.x * 64;
    int tid = threadIdx.x;
    int tx = tid & 15, ty = tid >> 4;
    float acc[4][8];
    #pragma unroll
    for (int i = 0; i < 4; i++)
        #pragma unroll
        for (int j = 0; j < 8; j++) acc[i][j] = 0.f;

    for (int kk = 0; kk < 64; kk += 16) {
        int m  = tid >> 2;
        int k4 = (tid & 3) * 4;
        float4 v = make_float4(0.f, 0.f, 0.f, 0.f);
        if (row0 + m < M)
            v = *(const float4*)(A + (size_t)(row0 + m) * 64 + kk + k4);
        As[k4 + 0][m] = v.x; As[k4 + 1][m] = v.y;
        As[k4 + 2][m] = v.z; As[k4 + 3][m] = v.w;
        #pragma unroll
        for (int t = 0; t < 2; t++) {
            int id = tid + t * 256;
            int k = id >> 5, n4 = (id & 31) * 4;
            *(float4*)(&Bs[k][n4]) = *(const float4*)(B + (size_t)(kk + k) * 128 + n4);
        }
        __syncthreads();
        #pragma unroll
        for (int k = 0; k < 16; k++) {
            float a[4], b[8];
            #pragma unroll
            for (int i = 0; i < 4; i++) a[i] = As[k][ty * 4 + i];
            #pragma unroll
            for (int j = 0; j < 8; j++) b[j] = Bs[k][tx + j * 16];
            #pragma unroll
            for (int i = 0; i < 4; i++)
                #pragma unroll
                for (int j = 0; j < 8; j++) acc[i][j] += a[i] * b[j];
        }
        __syncthreads();
    }
    #pragma unroll
    for (int i = 0; i < 4; i++) {
        int r = row0 + ty * 4 + i;
        if (r < M) {
            #pragma unroll
            for (int j = 0; j < 8; j++) {
                int c = tx + j * 16;
                C[(size_t)r * 128 + c] = acc[i][j] + bias[c];
            }
        }
    }
}

// ---------------------------------------------------------------------------
// base[e,:] = bf16( nodeW1[from[e],:] + ef[e,:16] @ W2[16,128] + (W2_b+W3_b) )
// 32 threads per edge (4 cols each), W2 columns in registers, 512 edges/block.
__global__ __launch_bounds__(256) void base_v2(
    const float* __restrict__ nodeW1, const int* __restrict__ from,
    const float* __restrict__ ef, const float* __restrict__ W2,
    const float* __restrict__ W2b, const float* __restrict__ W3b,
    bf16* __restrict__ baseB)
{
    int tid = threadIdx.x;
    int c0 = (tid & 31) * 4;
    int sub = tid >> 5;                  // 8 edge slots
    float4 w[16];
    #pragma unroll
    for (int k = 0; k < 16; k++) w[k] = *(const float4*)(W2 + k * 128 + c0);
    float4 bias;
    {
        float4 a = *(const float4*)(W2b + c0);
        float4 b = *(const float4*)(W3b + c0);
        bias = make_float4(a.x + b.x, a.y + b.y, a.z + b.z, a.w + b.w);
    }
    #pragma unroll 1
    for (int it = 0; it < 64; ++it) {
        int e = blockIdx.x * 512 + it * 8 + sub;
        if (e >= N_EDGES) break;
        const float* efr = ef + (size_t)e * 16;
        float4 nv = *(const float4*)(nodeW1 + (size_t)from[e] * 128 + c0);
        float4 acc = make_float4(bias.x + nv.x, bias.y + nv.y,
                                 bias.z + nv.z, bias.w + nv.w);
        #pragma unroll
        for (int k = 0; k < 16; k++) {
            float s = efr[k];
            acc.x += s * w[k].x; acc.y += s * w[k].y;
            acc.z += s * w[k].z; acc.w += s * w[k].w;
        }
        bf16x4 o;
        o[0] = (bf16)acc.x; o[1] = (bf16)acc.y; o[2] = (bf16)acc.z; o[3] = (bf16)acc.w;
        *(bf16x4*)(baseB + (size_t)e * 128 + c0) = o;
    }
}

// ---------------------------------------------------------------------------
// W3T[n][k] = bf16(W3[k][n]);  U2T[n][k] = bf16(U2[k][n])   (one-time)
__global__ __launch_bounds__(256) void prep_weights(
    const float* __restrict__ W3, const float* __restrict__ U2,
    bf16* __restrict__ W3T, bf16* __restrict__ U2T)
{
    int i = blockIdx.x * 256 + threadIdx.x;
    if (i < 128 * 128) {
        int k = i >> 7, n = i & 127;
        W3T[n * 128 + k] = (bf16)W3[k * 128 + n];
        U2T[n * 128 + k] = (bf16)U2[k * 128 + n];
    }
}

// ---------------------------------------------------------------------------
// Fused edge-step GEMM (bf16 MFMA), NO atomics:
//   A[e,:] = fused ? relu(base[e] + S[from[e]] - g[e^1]) : relu(base[e])
//   gout[e,:] = bf16(A @ B)        (B given transposed bf16 [n][k])
// Tile: 64 edges x 128 cols, K=128. e^1 stays in-tile; in-place gbuf is safe
// (all gbuf reads happen in the A-stage before __syncthreads + epilogue).
__global__ __launch_bounds__(256) void edge_mfma(
    const bf16* __restrict__ baseB, const bf16* __restrict__ gbuf,
    const bf16* __restrict__ Sprev, const int* __restrict__ from,
    const bf16* __restrict__ BT, bf16* __restrict__ gout, int fused)
{
    __shared__ bf16 As[64][136];    // +8 pad: row pitch 272B
    __shared__ bf16 Bs[128][136];
    int row0 = blockIdx.x * 64;
    int tid = threadIdx.x;

    #pragma unroll
    for (int t = 0; t < 8; t++) {
        int cid = tid + t * 256;
        int brow = cid >> 4, bcol = (cid & 15) * 8;
        *(bf16x8*)&Bs[brow][bcol] = *(const bf16x8*)(BT + (size_t)brow * 128 + bcol);
    }

    int r  = tid >> 2;
    int e  = row0 + r;
    int c0 = (tid & 3) * 32;
    if (!fused) {
        #pragma unroll
        for (int cc = 0; cc < 32; cc += 8) {
            int c = c0 + cc;
            bf16x8 bb = *(const bf16x8*)(baseB + (size_t)e * 128 + c);
            bf16x8 o;
            #pragma unroll
            for (int j = 0; j < 8; j++) o[j] = (bf16)fmaxf((float)bb[j], 0.f);
            *(bf16x8*)&As[r][c] = o;
        }
    } else {
        int fe = from[e];
        const bf16* sr = Sprev + (size_t)fe * 128;
        const bf16* gr = gbuf + (size_t)(e ^ 1) * 128;
        #pragma unroll
        for (int cc = 0; cc < 32; cc += 8) {
            int c = c0 + cc;
            bf16x8 bb = *(const bf16x8*)(baseB + (size_t)e * 128 + c);
            bf16x8 gg = *(const bf16x8*)(gr + c);
            bf16x8 ss = *(const bf16x8*)(sr + c);
            bf16x8 o;
            #pragma unroll
            for (int j = 0; j < 8; j++) {
                float v = (float)bb[j] + (float)ss[j] - (float)gg[j];
                o[j] = (bf16)fmaxf(v, 0.f);
            }
            *(bf16x8*)&As[r][c] = o;
        }
    }
    __syncthreads();

    int wave = tid >> 6, lane = tid & 63;
    int quad = lane >> 4, mr = lane & 15;
    int m0 = wave * 16;
    f32x4 acc[8];
    #pragma unroll
    for (int n = 0; n < 8; n++) acc[n] = (f32x4){0.f, 0.f, 0.f, 0.f};
    #pragma unroll
    for (int kt = 0; kt < 4; kt++) {
        bf16x8 a = *(const bf16x8*)&As[m0 + mr][kt * 32 + quad * 8];
        #pragma unroll
        for (int n = 0; n < 8; n++) {
            bf16x8 b = *(const bf16x8*)&Bs[n * 16 + mr][kt * 32 + quad * 8];
            acc[n] = __builtin_amdgcn_mfma_f32_16x16x32_bf16(a, b, acc[n], 0, 0, 0);
        }
    }

    // C/D layout: col = lane&15, row = quad*4 + reg
    #pragma unroll
    for (int n = 0; n < 8; n++) {
        int col = n * 16 + mr;
        #pragma unroll
        for (int reg = 0; reg < 4; reg++) {
            int rr = row0 + m0 + quad * 4 + reg;
            gout[(size_t)rr * 128 + col] = (bf16)acc[n][reg];
        }
    }
}

// ---------------------------------------------------------------------------
// CSR segment-sum gather. One wave per node; lane covers 2 cols.
// FINAL=0: S[n,:] = bf16( sum_{i in bucket n} g[se[i],:] )
// FINAL=1: agg[n,:] = fp32 sum of g[se[i]^1,:]   (== segment_sum by `to`)
template<int FINAL>
__global__ __launch_bounds__(256) void segsum(
    const bf16* __restrict__ g, const int* __restrict__ off,
    const int* __restrict__ se, bf16* __restrict__ Sout, float* __restrict__ aggout)
{
    int n = blockIdx.x * 4 + (threadIdx.x >> 6);
    if (n >= N_NODES) return;
    int lane = threadIdx.x & 63;
    int o0 = off[n], o1 = off[n + 1];
    float a0 = 0.f, a1 = 0.f;
    for (int i = o0; i < o1; ++i) {
        int e = se[i] ^ FINAL;
        bf16x2 v = *(const bf16x2*)(g + (size_t)e * 128 + lane * 2);
        a0 += (float)v[0];
        a1 += (float)v[1];
    }
    if (FINAL) {
        *(float2*)(aggout + (size_t)n * 128 + lane * 2) = make_float2(a0, a1);
    } else {
        bf16x2 o; o[0] = (bf16)a0; o[1] = (bf16)a1;
        *(bf16x2*)(Sout + (size_t)n * 128 + lane * 2) = o;
    }
}

// ---------------------------------------------------------------------------
// out[n,:] = relu(U1x[n,:] + agg[n,:] + deg[n] * U2_b[:])
__global__ __launch_bounds__(256) void final_out(
    const float* __restrict__ U1x, const float* __restrict__ agg,
    const int* __restrict__ deg, const float* __restrict__ U2b,
    float* __restrict__ out)
{
    int gid = blockIdx.x * 256 + threadIdx.x;
    int n  = gid >> 5;
    if (n >= N_NODES) return;
    int c4 = gid & 31;
    float d = (float)deg[n];
    float4 a  = *(const float4*)(U1x + (size_t)n * 128 + c4 * 4);
    float4 ag = *(const float4*)(agg + (size_t)n * 128 + c4 * 4);
    float4 ub = *(const float4*)(U2b + c4 * 4);
    float4 r;
    r.x = fmaxf(a.x + ag.x + d * ub.x, 0.f);
    r.y = fmaxf(a.y + ag.y + d * ub.y, 0.f);
    r.z = fmaxf(a.z + ag.z + d * ub.z, 0.f);
    r.w = fmaxf(a.w + ag.w + d * ub.w, 0.f);
    *(float4*)(out + (size_t)n * 128 + c4 * 4) = r;
}

// ---------------------------------------------------------------------------
extern "C" void kernel_launch(void* const* d_in, const int* in_sizes, int n_in,
                              void* d_out, int out_size, void* d_ws, size_t ws_size,
                              hipStream_t stream) {
    const float* nf  = (const float*)d_in[0];
    const float* ef  = (const float*)d_in[1];
    // d_in[2] edge_hiddens: zeros -> h1 = relu(base); first GEMM uses fused=0
    const int* edges = (const int*)d_in[3];
    const int* from  = edges;
    const float* W1w = (const float*)d_in[4];
    const float* W1b = (const float*)d_in[5];
    const float* W2w = (const float*)d_in[6];
    const float* W2b = (const float*)d_in[7];
    const float* W3w = (const float*)d_in[8];
    const float* W3b = (const float*)d_in[9];
    const float* U1w = (const float*)d_in[10];
    const float* U1b = (const float*)d_in[11];
    const float* U2w = (const float*)d_in[12];
    const float* U2b = (const float*)d_in[13];
    float* out = (float*)d_out;

    const size_t NODE_MAT = (size_t)N_NODES * 128;
    const size_t EDGE_MAT = (size_t)N_EDGES * 128;
    char* w = (char*)d_ws;
    float* nodeW1 = (float*)w; w += NODE_MAT * 4;        // reused as U1x
    float* agg    = (float*)w; w += NODE_MAT * 4;
    bf16*  S      = (bf16*)w;  w += NODE_MAT * 2;
    bf16*  baseB  = (bf16*)w;  w += EDGE_MAT * 2;
    bf16*  gbuf   = (bf16*)w;  w += EDGE_MAT * 2;
    bf16*  W3T    = (bf16*)w;  w += 128 * 128 * 2;
    bf16*  U2T    = (bf16*)w;  w += 128 * 128 * 2;
    int*   deg    = (int*)w;   w += (size_t)N_NODES * 4;
    int*   off    = (int*)w;   w += (size_t)(N_NODES + 1) * 4;
    int*   cursor = (int*)w;   w += (size_t)N_NODES * 4;
    int*   bsum   = (int*)w;   w += (size_t)SCAN_BLOCKS * 4;
    int*   bpref  = (int*)w;   w += (size_t)SCAN_BLOCKS * 4;
    int*   se     = (int*)w;   w += (size_t)N_EDGES * 4;

    // ---- CSR build ----
    hipMemsetAsync(deg, 0, (size_t)N_NODES * 4, stream);
    deg_hist<<<(N_EDGES + 255) / 256, 256, 0, stream>>>(from, deg, N_EDGES);
    block_sums<<<SCAN_BLOCKS, 256, 0, stream>>>(deg, bsum);
    scan_partials<<<1, 256, 0, stream>>>(bsum, bpref, off);
    block_scan<<<SCAN_BLOCKS, 256, 0, stream>>>(deg, bpref, off, cursor);
    scatter_csr<<<(N_EDGES + 255) / 256, 256, 0, stream>>>(from, cursor, se, N_EDGES);

    // ---- loop-invariant precompute ----
    prep_weights<<<(128 * 128 + 255) / 256, 256, 0, stream>>>(W3w, U2w, W3T, U2T);
    node_gemm<<<(N_NODES + 63) / 64, 256, 0, stream>>>(nf, W1w, W1b, nodeW1, N_NODES);
    base_v2<<<(N_EDGES + 511) / 512, 256, 0, stream>>>(nodeW1, from, ef, W2w, W2b, W3b, baseB);

    // ---- message passing: h1 = relu(base) folded into first GEMM ----
    edge_mfma<<<N_EDGES / 64, 256, 0, stream>>>(baseB, gbuf, S, from, W3T, gbuf, 0);
    segsum<0><<<(N_NODES + 3) / 4, 256, 0, stream>>>(gbuf, off, se, S, agg);
    for (int it = 1; it < 5; ++it) {
        edge_mfma<<<N_EDGES / 64, 256, 0, stream>>>(baseB, gbuf, S, from, W3T, gbuf, 1);
        segsum<0><<<(N_NODES + 3) / 4, 256, 0, stream>>>(gbuf, off, se, S, agg);
    }
    // ---- readout: h6 built in-flight, B = U2T; then to-side segment sum ----
    edge_mfma<<<N_EDGES / 64, 256, 0, stream>>>(baseB, gbuf, S, from, U2T, gbuf, 1);
    segsum<1><<<(N_NODES + 3) / 4, 256, 0, stream>>>(gbuf, off, se, S, agg);

    node_gemm<<<(N_NODES + 63) / 64, 256, 0, stream>>>(nf, U1w, U1b, nodeW1, N_NODES);
    final_out<<<(N_NODES * 32 + 255) / 256, 256, 0, stream>>>(nodeW1, agg, deg, U2b, out);
}

// Round 4
// 1690.057 us; speedup vs baseline: 2.1794x; 1.0512x over previous
//
#include <hip/hip_runtime.h>
#include <hip/hip_bf16.h>

#define N_NODES 100000
#define N_EDGES 600000
#define SCAN_BLOCKS ((N_NODES + 255) / 256)   // 391

typedef __bf16 bf16;
typedef __bf16 bf16x2 __attribute__((ext_vector_type(2)));
typedef __bf16 bf16x4 __attribute__((ext_vector_type(4)));
typedef __bf16 bf16x8 __attribute__((ext_vector_type(8)));
typedef float f32x4 __attribute__((ext_vector_type(4)));

// ---------------------------------------------------------------------------
// deg[n] = #edges with from==n (== to-degree by reverse-pair symmetry)
__global__ void deg_hist(const int* __restrict__ from, int* __restrict__ deg, int E) {
    int e = blockIdx.x * blockDim.x + threadIdx.x;
    if (e < E) atomicAdd(&deg[from[e]], 1);
}

// ---- CSR build ----
__global__ __launch_bounds__(256) void block_sums(
    const int* __restrict__ deg, int* __restrict__ bsum)
{
    __shared__ int s[256];
    int i = blockIdx.x * 256 + threadIdx.x;
    s[threadIdx.x] = (i < N_NODES) ? deg[i] : 0;
    __syncthreads();
    for (int st = 128; st > 0; st >>= 1) {
        if (threadIdx.x < st) s[threadIdx.x] += s[threadIdx.x + st];
        __syncthreads();
    }
    if (threadIdx.x == 0) bsum[blockIdx.x] = s[0];
}

__global__ __launch_bounds__(256) void scan_partials(
    const int* __restrict__ bsum, int* __restrict__ bpref, int* __restrict__ off)
{
    __shared__ int s[SCAN_BLOCKS];
    for (int i = threadIdx.x; i < SCAN_BLOCKS; i += 256) s[i] = bsum[i];
    __syncthreads();
    if (threadIdx.x == 0) {
        int run = 0;
        for (int i = 0; i < SCAN_BLOCKS; i++) { int t = s[i]; s[i] = run; run += t; }
        off[N_NODES] = run;   // == N_EDGES
    }
    __syncthreads();
    for (int i = threadIdx.x; i < SCAN_BLOCKS; i += 256) bpref[i] = s[i];
}

__global__ __launch_bounds__(256) void block_scan(
    const int* __restrict__ deg, const int* __restrict__ bpref,
    int* __restrict__ off, int* __restrict__ cursor)
{
    __shared__ int s[256];
    int i = blockIdx.x * 256 + threadIdx.x;
    int v = (i < N_NODES) ? deg[i] : 0;
    s[threadIdx.x] = v;
    __syncthreads();
    for (int st = 1; st < 256; st <<= 1) {
        int x = (threadIdx.x >= st) ? s[threadIdx.x - st] : 0;
        __syncthreads();
        s[threadIdx.x] += x;
        __syncthreads();
    }
    if (i < N_NODES) {
        int o = bpref[blockIdx.x] + s[threadIdx.x] - v;   // exclusive
        off[i] = o;
        cursor[i] = o;
    }
}

// se[p] = e (sorted by from), rank[e] = p
__global__ void scatter_csr(const int* __restrict__ from, int* __restrict__ cursor,
                            int* __restrict__ se, int* __restrict__ rank, int E) {
    int e = blockIdx.x * blockDim.x + threadIdx.x;
    if (e < E) {
        int p = atomicAdd(&cursor[from[e]], 1);
        se[p] = e;
        rank[e] = p;
    }
}

// fromP[i] = from[se[i]]; backP[i] = rank[se[i]^1]
__global__ void make_maps(const int* __restrict__ se, const int* __restrict__ from,
                          const int* __restrict__ rank,
                          int* __restrict__ fromP, int* __restrict__ backP, int E) {
    int i = blockIdx.x * blockDim.x + threadIdx.x;
    if (i < E) {
        int e = se[i];
        fromP[i] = from[e];
        backP[i] = rank[e ^ 1];
    }
}

// ---------------------------------------------------------------------------
// C[M,128] = A[M,64] @ B[64,128] + bias   (node-side GEMM, K=64, fp32 vector)
__global__ __launch_bounds__(256) void node_gemm(
    const float* __restrict__ A, const float* __restrict__ B,
    const float* __restrict__ bias, float* __restrict__ C, int M)
{
    __shared__ float As[16][65];
    __shared__ float Bs[16][128];
    int row0 = blockIdx.x * 64;
    int tid = threadIdx.x;
    int tx = tid & 15, ty = tid >> 4;
    float acc[4][8];
    #pragma unroll
    for (int i = 0; i < 4; i++)
        #pragma unroll
        for (int j = 0; j < 8; j++) acc[i][j] = 0.f;

    for (int kk = 0; kk < 64; kk += 16) {
        int m  = tid >> 2;
        int k4 = (tid & 3) * 4;
        float4 v = make_float4(0.f, 0.f, 0.f, 0.f);
        if (row0 + m < M)
            v = *(const float4*)(A + (size_t)(row0 + m) * 64 + kk + k4);
        As[k4 + 0][m] = v.x; As[k4 + 1][m] = v.y;
        As[k4 + 2][m] = v.z; As[k4 + 3][m] = v.w;
        #pragma unroll
        for (int t = 0; t < 2; t++) {
            int id = tid + t * 256;
            int k = id >> 5, n4 = (id & 31) * 4;
            *(float4*)(&Bs[k][n4]) = *(const float4*)(B + (size_t)(kk + k) * 128 + n4);
        }
        __syncthreads();
        #pragma unroll
        for (int k = 0; k < 16; k++) {
            float a[4], b[8];
            #pragma unroll
            for (int i = 0; i < 4; i++) a[i] = As[k][ty * 4 + i];
            #pragma unroll
            for (int j = 0; j < 8; j++) b[j] = Bs[k][tx + j * 16];
            #pragma unroll
            for (int i = 0; i < 4; i++)
                #pragma unroll
                for (int j = 0; j < 8; j++) acc[i][j] += a[i] * b[j];
        }
        __syncthreads();
    }
    #pragma unroll
    for (int i = 0; i < 4; i++) {
        int r = row0 + ty * 4 + i;
        if (r < M) {
            #pragma unroll
            for (int j = 0; j < 8; j++) {
                int c = tx + j * 16;
                C[(size_t)r * 128 + c] = acc[i][j] + bias[c];
            }
        }
    }
}

// ---------------------------------------------------------------------------
// baseP[i,:] = bf16( nodeW1[fromP[i],:] + ef[se[i],:16]@W2 + (W2_b+W3_b) )
// Sorted edge space: nodeW1 row reuse across consecutive i; ef is a 64B gather.
__global__ __launch_bounds__(256) void base_sorted(
    const float* __restrict__ nodeW1, const int* __restrict__ fromP,
    const int* __restrict__ se, const float* __restrict__ ef,
    const float* __restrict__ W2, const float* __restrict__ W2b,
    const float* __restrict__ W3b, bf16* __restrict__ baseP)
{
    int tid = threadIdx.x;
    int c0 = (tid & 31) * 4;
    int sub = tid >> 5;                  // 8 edge slots
    float4 w[16];
    #pragma unroll
    for (int k = 0; k < 16; k++) w[k] = *(const float4*)(W2 + k * 128 + c0);
    float4 bias;
    {
        float4 a = *(const float4*)(W2b + c0);
        float4 b = *(const float4*)(W3b + c0);
        bias = make_float4(a.x + b.x, a.y + b.y, a.z + b.z, a.w + b.w);
    }
    #pragma unroll 1
    for (int it = 0; it < 64; ++it) {
        int i = blockIdx.x * 512 + it * 8 + sub;
        if (i >= N_EDGES) break;
        const float* efr = ef + (size_t)se[i] * 16;
        float4 nv = *(const float4*)(nodeW1 + (size_t)fromP[i] * 128 + c0);
        float4 acc = make_float4(bias.x + nv.x, bias.y + nv.y,
                                 bias.z + nv.z, bias.w + nv.w);
        #pragma unroll
        for (int k = 0; k < 16; k++) {
            float s = efr[k];
            acc.x += s * w[k].x; acc.y += s * w[k].y;
            acc.z += s * w[k].z; acc.w += s * w[k].w;
        }
        bf16x4 o;
        o[0] = (bf16)acc.x; o[1] = (bf16)acc.y; o[2] = (bf16)acc.z; o[3] = (bf16)acc.w;
        *(bf16x4*)(baseP + (size_t)i * 128 + c0) = o;
    }
}

// ---------------------------------------------------------------------------
// W3T[n][k] = bf16(W3[k][n]);  U2T[n][k] = bf16(U2[k][n])   (one-time)
__global__ __launch_bounds__(256) void prep_weights(
    const float* __restrict__ W3, const float* __restrict__ U2,
    bf16* __restrict__ W3T, bf16* __restrict__ U2T)
{
    int i = blockIdx.x * 256 + threadIdx.x;
    if (i < 128 * 128) {
        int k = i >> 7, n = i & 127;
        W3T[n * 128 + k] = (bf16)W3[k * 128 + n];
        U2T[n * 128 + k] = (bf16)U2[k * 128 + n];
    }
}

// ---------------------------------------------------------------------------
// Fused edge-step GEMM (bf16 MFMA), sorted edge space:
//   A[i,:] = fused ? relu(baseP[i] + S[fromP[i]] - gin[backP[i]]) : relu(baseP[i])
//   gout[i,:] = bf16(A @ B)     (B transposed bf16 [n][k]; gin/gout ping-pong)
__global__ __launch_bounds__(256) void edge_mfma_s(
    const bf16* __restrict__ baseP, const bf16* __restrict__ gin,
    const bf16* __restrict__ S, const int* __restrict__ fromP,
    const int* __restrict__ backP, const bf16* __restrict__ BT,
    bf16* __restrict__ gout, int fused)
{
    __shared__ bf16 As[64][136];    // +8 pad: row pitch 272B
    __shared__ bf16 Bs[128][136];
    int row0 = blockIdx.x * 64;
    int tid = threadIdx.x;

    #pragma unroll
    for (int t = 0; t < 8; t++) {
        int cid = tid + t * 256;
        int brow = cid >> 4, bcol = (cid & 15) * 8;
        *(bf16x8*)&Bs[brow][bcol] = *(const bf16x8*)(BT + (size_t)brow * 128 + bcol);
    }

    int r  = tid >> 2;
    int i  = row0 + r;
    int c0 = (tid & 3) * 32;
    if (!fused) {
        #pragma unroll
        for (int cc = 0; cc < 32; cc += 8) {
            int c = c0 + cc;
            bf16x8 bb = *(const bf16x8*)(baseP + (size_t)i * 128 + c);
            bf16x8 o;
            #pragma unroll
            for (int j = 0; j < 8; j++) o[j] = (bf16)fmaxf((float)bb[j], 0.f);
            *(bf16x8*)&As[r][c] = o;
        }
    } else {
        const bf16* sr = S + (size_t)fromP[i] * 128;
        const bf16* gr = gin + (size_t)backP[i] * 128;
        #pragma unroll
        for (int cc = 0; cc < 32; cc += 8) {
            int c = c0 + cc;
            bf16x8 bb = *(const bf16x8*)(baseP + (size_t)i * 128 + c);
            bf16x8 gg = *(const bf16x8*)(gr + c);
            bf16x8 ss = *(const bf16x8*)(sr + c);
            bf16x8 o;
            #pragma unroll
            for (int j = 0; j < 8; j++) {
                float v = (float)bb[j] + (float)ss[j] - (float)gg[j];
                o[j] = (bf16)fmaxf(v, 0.f);
            }
            *(bf16x8*)&As[r][c] = o;
        }
    }
    __syncthreads();

    int wave = tid >> 6, lane = tid & 63;
    int quad = lane >> 4, mr = lane & 15;
    int m0 = wave * 16;
    f32x4 acc[8];
    #pragma unroll
    for (int n = 0; n < 8; n++) acc[n] = (f32x4){0.f, 0.f, 0.f, 0.f};
    #pragma unroll
    for (int kt = 0; kt < 4; kt++) {
        bf16x8 a = *(const bf16x8*)&As[m0 + mr][kt * 32 + quad * 8];
        #pragma unroll
        for (int n = 0; n < 8; n++) {
            bf16x8 b = *(const bf16x8*)&Bs[n * 16 + mr][kt * 32 + quad * 8];
            acc[n] = __builtin_amdgcn_mfma_f32_16x16x32_bf16(a, b, acc[n], 0, 0, 0);
        }
    }

    // C/D layout: col = lane&15, row = quad*4 + reg
    #pragma unroll
    for (int n = 0; n < 8; n++) {
        int col = n * 16 + mr;
        #pragma unroll
        for (int reg = 0; reg < 4; reg++) {
            int rr = row0 + m0 + quad * 4 + reg;
            gout[(size_t)rr * 128 + col] = (bf16)acc[n][reg];
        }
    }
}

// ---------------------------------------------------------------------------
// Streaming segment sum: S[n,:] = bf16( sum_{i=off[n]}^{off[n+1]} g[i,:] )
// g is in CSR-sorted order -> contiguous rows per node. One wave per node.
__global__ __launch_bounds__(256) void segsum_stream(
    const bf16* __restrict__ g, const int* __restrict__ off, bf16* __restrict__ S)
{
    int n = blockIdx.x * 4 + (threadIdx.x >> 6);
    if (n >= N_NODES) return;
    int lane = threadIdx.x & 63;
    int o0 = off[n], o1 = off[n + 1];
    float a0 = 0.f, a1 = 0.f;
    for (int i = o0; i < o1; ++i) {
        bf16x2 v = *(const bf16x2*)(g + (size_t)i * 128 + lane * 2);
        a0 += (float)v[0];
        a1 += (float)v[1];
    }
    bf16x2 o; o[0] = (bf16)a0; o[1] = (bf16)a1;
    *(bf16x2*)(S + (size_t)n * 128 + lane * 2) = o;
}

// to-side readout: agg[n,:] = fp32 sum_{i in bucket n} g[backP[i],:]
__global__ __launch_bounds__(256) void segsum_final(
    const bf16* __restrict__ g, const int* __restrict__ off,
    const int* __restrict__ backP, float* __restrict__ agg)
{
    int n = blockIdx.x * 4 + (threadIdx.x >> 6);
    if (n >= N_NODES) return;
    int lane = threadIdx.x & 63;
    int o0 = off[n], o1 = off[n + 1];
    float a0 = 0.f, a1 = 0.f;
    for (int i = o0; i < o1; ++i) {
        int e = backP[i];
        bf16x2 v = *(const bf16x2*)(g + (size_t)e * 128 + lane * 2);
        a0 += (float)v[0];
        a1 += (float)v[1];
    }
    *(float2*)(agg + (size_t)n * 128 + lane * 2) = make_float2(a0, a1);
}

// ---------------------------------------------------------------------------
// out[n,:] = relu(U1x[n,:] + agg[n,:] + deg[n] * U2_b[:])
__global__ __launch_bounds__(256) void final_out(
    const float* __restrict__ U1x, const float* __restrict__ agg,
    const int* __restrict__ deg, const float* __restrict__ U2b,
    float* __restrict__ out)
{
    int gid = blockIdx.x * 256 + threadIdx.x;
    int n  = gid >> 5;
    if (n >= N_NODES) return;
    int c4 = gid & 31;
    float d = (float)deg[n];
    float4 a  = *(const float4*)(U1x + (size_t)n * 128 + c4 * 4);
    float4 ag = *(const float4*)(agg + (size_t)n * 128 + c4 * 4);
    float4 ub = *(const float4*)(U2b + c4 * 4);
    float4 r;
    r.x = fmaxf(a.x + ag.x + d * ub.x, 0.f);
    r.y = fmaxf(a.y + ag.y + d * ub.y, 0.f);
    r.z = fmaxf(a.z + ag.z + d * ub.z, 0.f);
    r.w = fmaxf(a.w + ag.w + d * ub.w, 0.f);
    *(float4*)(out + (size_t)n * 128 + c4 * 4) = r;
}

// ---------------------------------------------------------------------------
extern "C" void kernel_launch(void* const* d_in, const int* in_sizes, int n_in,
                              void* d_out, int out_size, void* d_ws, size_t ws_size,
                              hipStream_t stream) {
    const float* nf  = (const float*)d_in[0];
    const float* ef  = (const float*)d_in[1];
    // d_in[2] edge_hiddens: zeros -> h1 = relu(base); first GEMM uses fused=0
    const int* edges = (const int*)d_in[3];
    const int* from  = edges;
    const float* W1w = (const float*)d_in[4];
    const float* W1b = (const float*)d_in[5];
    const float* W2w = (const float*)d_in[6];
    const float* W2b = (const float*)d_in[7];
    const float* W3w = (const float*)d_in[8];
    const float* W3b = (const float*)d_in[9];
    const float* U1w = (const float*)d_in[10];
    const float* U1b = (const float*)d_in[11];
    const float* U2w = (const float*)d_in[12];
    const float* U2b = (const float*)d_in[13];
    float* out = (float*)d_out;

    const size_t NODE_MAT = (size_t)N_NODES * 128;
    const size_t EDGE_MAT = (size_t)N_EDGES * 128;
    char* w = (char*)d_ws;
    float* nodeW1 = (float*)w; w += NODE_MAT * 4;        // reused as U1x
    float* agg    = (float*)w; w += NODE_MAT * 4;
    bf16*  S      = (bf16*)w;  w += NODE_MAT * 2;
    bf16*  baseP  = (bf16*)w;  w += EDGE_MAT * 2;
    bf16*  g0     = (bf16*)w;  w += EDGE_MAT * 2;
    bf16*  g1     = (bf16*)w;  w += EDGE_MAT * 2;
    bf16*  W3T    = (bf16*)w;  w += 128 * 128 * 2;
    bf16*  U2T    = (bf16*)w;  w += 128 * 128 * 2;
    int*   deg    = (int*)w;   w += (size_t)N_NODES * 4;
    int*   off    = (int*)w;   w += (size_t)(N_NODES + 1) * 4;
    int*   cursor = (int*)w;   w += (size_t)N_NODES * 4;
    int*   bsum   = (int*)w;   w += (size_t)SCAN_BLOCKS * 4;
    int*   bpref  = (int*)w;   w += (size_t)SCAN_BLOCKS * 4;
    int*   se     = (int*)w;   w += (size_t)N_EDGES * 4;
    int*   rank   = (int*)w;   w += (size_t)N_EDGES * 4;
    int*   fromP  = (int*)w;   w += (size_t)N_EDGES * 4;
    int*   backP  = (int*)w;   w += (size_t)N_EDGES * 4;

    // ---- CSR build + sorted-space maps ----
    hipMemsetAsync(deg, 0, (size_t)N_NODES * 4, stream);
    deg_hist<<<(N_EDGES + 255) / 256, 256, 0, stream>>>(from, deg, N_EDGES);
    block_sums<<<SCAN_BLOCKS, 256, 0, stream>>>(deg, bsum);
    scan_partials<<<1, 256, 0, stream>>>(bsum, bpref, off);
    block_scan<<<SCAN_BLOCKS, 256, 0, stream>>>(deg, bpref, off, cursor);
    scatter_csr<<<(N_EDGES + 255) / 256, 256, 0, stream>>>(from, cursor, se, rank, N_EDGES);
    make_maps<<<(N_EDGES + 255) / 256, 256, 0, stream>>>(se, from, rank, fromP, backP, N_EDGES);

    // ---- loop-invariant precompute ----
    prep_weights<<<(128 * 128 + 255) / 256, 256, 0, stream>>>(W3w, U2w, W3T, U2T);
    node_gemm<<<(N_NODES + 63) / 64, 256, 0, stream>>>(nf, W1w, W1b, nodeW1, N_NODES);
    base_sorted<<<(N_EDGES + 511) / 512, 256, 0, stream>>>(
        nodeW1, fromP, se, ef, W2w, W2b, W3b, baseP);

    // ---- message passing (sorted space, ping-pong g) ----
    bf16* G[2] = {g0, g1};
    edge_mfma_s<<<N_EDGES / 64, 256, 0, stream>>>(
        baseP, G[0], S, fromP, backP, W3T, G[0], 0);
    segsum_stream<<<(N_NODES + 3) / 4, 256, 0, stream>>>(G[0], off, S);
    int cur = 0;
    for (int it = 1; it < 5; ++it) {
        edge_mfma_s<<<N_EDGES / 64, 256, 0, stream>>>(
            baseP, G[cur], S, fromP, backP, W3T, G[cur ^ 1], 1);
        cur ^= 1;
        segsum_stream<<<(N_NODES + 3) / 4, 256, 0, stream>>>(G[cur], off, S);
    }
    // ---- readout: h6 built in-flight, B = U2T; then to-side segment sum ----
    edge_mfma_s<<<N_EDGES / 64, 256, 0, stream>>>(
        baseP, G[cur], S, fromP, backP, U2T, G[cur ^ 1], 1);
    cur ^= 1;
    segsum_final<<<(N_NODES + 3) / 4, 256, 0, stream>>>(G[cur], off, backP, agg);

    node_gemm<<<(N_NODES + 63) / 64, 256, 0, stream>>>(nf, U1w, U1b, nodeW1, N_NODES);
    final_out<<<(N_NODES * 32 + 255) / 256, 256, 0, stream>>>(nodeW1, agg, deg, U2b, out);
}

// Round 5
// 1654.756 us; speedup vs baseline: 2.2259x; 1.0213x over previous
//
#include <hip/hip_runtime.h>
#include <hip/hip_bf16.h>

#define N_NODES 100000
#define N_EDGES 600000
#define SCAN_BLOCKS ((N_NODES + 255) / 256)   // 391

typedef __bf16 bf16;
typedef __bf16 bf16x2 __attribute__((ext_vector_type(2)));
typedef __bf16 bf16x4 __attribute__((ext_vector_type(4)));
typedef __bf16 bf16x8 __attribute__((ext_vector_type(8)));
typedef float f32x4 __attribute__((ext_vector_type(4)));

// ---------------------------------------------------------------------------
// deg[n] = #edges with from==n (== to-degree by reverse-pair symmetry)
__global__ void deg_hist(const int* __restrict__ from, int* __restrict__ deg, int E) {
    int e = blockIdx.x * blockDim.x + threadIdx.x;
    if (e < E) atomicAdd(&deg[from[e]], 1);
}

// ---- CSR build ----
__global__ __launch_bounds__(256) void block_sums(
    const int* __restrict__ deg, int* __restrict__ bsum)
{
    __shared__ int s[256];
    int i = blockIdx.x * 256 + threadIdx.x;
    s[threadIdx.x] = (i < N_NODES) ? deg[i] : 0;
    __syncthreads();
    for (int st = 128; st > 0; st >>= 1) {
        if (threadIdx.x < st) s[threadIdx.x] += s[threadIdx.x + st];
        __syncthreads();
    }
    if (threadIdx.x == 0) bsum[blockIdx.x] = s[0];
}

__global__ __launch_bounds__(256) void scan_partials(
    const int* __restrict__ bsum, int* __restrict__ bpref, int* __restrict__ off)
{
    __shared__ int s[SCAN_BLOCKS];
    for (int i = threadIdx.x; i < SCAN_BLOCKS; i += 256) s[i] = bsum[i];
    __syncthreads();
    if (threadIdx.x == 0) {
        int run = 0;
        for (int i = 0; i < SCAN_BLOCKS; i++) { int t = s[i]; s[i] = run; run += t; }
        off[N_NODES] = run;   // == N_EDGES
    }
    __syncthreads();
    for (int i = threadIdx.x; i < SCAN_BLOCKS; i += 256) bpref[i] = s[i];
}

__global__ __launch_bounds__(256) void block_scan(
    const int* __restrict__ deg, const int* __restrict__ bpref,
    int* __restrict__ off, int* __restrict__ cursor)
{
    __shared__ int s[256];
    int i = blockIdx.x * 256 + threadIdx.x;
    int v = (i < N_NODES) ? deg[i] : 0;
    s[threadIdx.x] = v;
    __syncthreads();
    for (int st = 1; st < 256; st <<= 1) {
        int x = (threadIdx.x >= st) ? s[threadIdx.x - st] : 0;
        __syncthreads();
        s[threadIdx.x] += x;
        __syncthreads();
    }
    if (i < N_NODES) {
        int o = bpref[blockIdx.x] + s[threadIdx.x] - v;   // exclusive
        off[i] = o;
        cursor[i] = o;
    }
}

// se[p] = e (sorted by from), rank[e] = p
__global__ void scatter_csr(const int* __restrict__ from, int* __restrict__ cursor,
                            int* __restrict__ se, int* __restrict__ rank, int E) {
    int e = blockIdx.x * blockDim.x + threadIdx.x;
    if (e < E) {
        int p = atomicAdd(&cursor[from[e]], 1);
        se[p] = e;
        rank[e] = p;
    }
}

// fromP[i] = from[se[i]]; backP[i] = rank[se[i]^1]
__global__ void make_maps(const int* __restrict__ se, const int* __restrict__ from,
                          const int* __restrict__ rank,
                          int* __restrict__ fromP, int* __restrict__ backP, int E) {
    int i = blockIdx.x * blockDim.x + threadIdx.x;
    if (i < E) {
        int e = se[i];
        fromP[i] = from[e];
        backP[i] = rank[e ^ 1];
    }
}

// ---------------------------------------------------------------------------
// C[M,128] = A[M,64] @ B[64,128] + bias   (node-side GEMM, K=64, fp32 vector)
__global__ __launch_bounds__(256) void node_gemm(
    const float* __restrict__ A, const float* __restrict__ B,
    const float* __restrict__ bias, float* __restrict__ C, int M)
{
    __shared__ float As[16][65];
    __shared__ float Bs[16][128];
    int row0 = blockIdx.x * 64;
    int tid = threadIdx.x;
    int tx = tid & 15, ty = tid >> 4;
    float acc[4][8];
    #pragma unroll
    for (int i = 0; i < 4; i++)
        #pragma unroll
        for (int j = 0; j < 8; j++) acc[i][j] = 0.f;

    for (int kk = 0; kk < 64; kk += 16) {
        int m  = tid >> 2;
        int k4 = (tid & 3) * 4;
        float4 v = make_float4(0.f, 0.f, 0.f, 0.f);
        if (row0 + m < M)
            v = *(const float4*)(A + (size_t)(row0 + m) * 64 + kk + k4);
        As[k4 + 0][m] = v.x; As[k4 + 1][m] = v.y;
        As[k4 + 2][m] = v.z; As[k4 + 3][m] = v.w;
        #pragma unroll
        for (int t = 0; t < 2; t++) {
            int id = tid + t * 256;
            int k = id >> 5, n4 = (id & 31) * 4;
            *(float4*)(&Bs[k][n4]) = *(const float4*)(B + (size_t)(kk + k) * 128 + n4);
        }
        __syncthreads();
        #pragma unroll
        for (int k = 0; k < 16; k++) {
            float a[4], b[8];
            #pragma unroll
            for (int i = 0; i < 4; i++) a[i] = As[k][ty * 4 + i];
            #pragma unroll
            for (int j = 0; j < 8; j++) b[j] = Bs[k][tx + j * 16];
            #pragma unroll
            for (int i = 0; i < 4; i++)
                #pragma unroll
                for (int j = 0; j < 8; j++) acc[i][j] += a[i] * b[j];
        }
        __syncthreads();
    }
    #pragma unroll
    for (int i = 0; i < 4; i++) {
        int r = row0 + ty * 4 + i;
        if (r < M) {
            #pragma unroll
            for (int j = 0; j < 8; j++) {
                int c = tx + j * 16;
                C[(size_t)r * 128 + c] = acc[i][j] + bias[c];
            }
        }
    }
}

// ---------------------------------------------------------------------------
// baseP[i,:] = bf16( nodeW1[fromP[i],:] + ef[se[i],:16]@W2 + (W2_b+W3_b) )
__global__ __launch_bounds__(256) void base_sorted(
    const float* __restrict__ nodeW1, const int* __restrict__ fromP,
    const int* __restrict__ se, const float* __restrict__ ef,
    const float* __restrict__ W2, const float* __restrict__ W2b,
    const float* __restrict__ W3b, bf16* __restrict__ baseP)
{
    int tid = threadIdx.x;
    int c0 = (tid & 31) * 4;
    int sub = tid >> 5;                  // 8 edge slots
    float4 w[16];
    #pragma unroll
    for (int k = 0; k < 16; k++) w[k] = *(const float4*)(W2 + k * 128 + c0);
    float4 bias;
    {
        float4 a = *(const float4*)(W2b + c0);
        float4 b = *(const float4*)(W3b + c0);
        bias = make_float4(a.x + b.x, a.y + b.y, a.z + b.z, a.w + b.w);
    }
    #pragma unroll 1
    for (int it = 0; it < 64; ++it) {
        int i = blockIdx.x * 512 + it * 8 + sub;
        if (i >= N_EDGES) break;
        const float* efr = ef + (size_t)se[i] * 16;
        float4 nv = *(const float4*)(nodeW1 + (size_t)fromP[i] * 128 + c0);
        float4 acc = make_float4(bias.x + nv.x, bias.y + nv.y,
                                 bias.z + nv.z, bias.w + nv.w);
        #pragma unroll
        for (int k = 0; k < 16; k++) {
            float s = efr[k];
            acc.x += s * w[k].x; acc.y += s * w[k].y;
            acc.z += s * w[k].z; acc.w += s * w[k].w;
        }
        bf16x4 o;
        o[0] = (bf16)acc.x; o[1] = (bf16)acc.y; o[2] = (bf16)acc.z; o[3] = (bf16)acc.w;
        *(bf16x4*)(baseP + (size_t)i * 128 + c0) = o;
    }
}

// ---------------------------------------------------------------------------
// W3T[n][k] = bf16(W3[k][n]);  U2T[n][k] = bf16(U2[k][n])   (one-time)
__global__ __launch_bounds__(256) void prep_weights(
    const float* __restrict__ W3, const float* __restrict__ U2,
    bf16* __restrict__ W3T, bf16* __restrict__ U2T)
{
    int i = blockIdx.x * 256 + threadIdx.x;
    if (i < 128 * 128) {
        int k = i >> 7, n = i & 127;
        W3T[n * 128 + k] = (bf16)W3[k * 128 + n];
        U2T[n * 128 + k] = (bf16)U2[k * 128 + n];
    }
}

// ---------------------------------------------------------------------------
// Edge-step GEMM v2 (bf16 MFMA), sorted edge space, no A-tile LDS, no barrier
// in the main loop:
//   A[i,:] = fused ? relu(baseP[i] + S[fromP[i]] - gin[backP[i]]) : relu(baseP[i])
//   gout[i,:] = bf16(A @ B)     (B transposed bf16 [n][k]; gin/gout ping-pong)
// Block = 256 rows (wave w owns rows w*64..w*64+63, in 4 groups of 16).
// B staged once per block into LDS in fragment-major order:
//   chunk c = (n*4+kt)*64 + quad*16 + mr  holds BT[n*16+mr][kt*32+quad*8 ..+8]
// so each MFMA b-frag read is lane-consecutive 16B (conflict-free).
__global__ __launch_bounds__(256) void edge_mfma_v2(
    const bf16* __restrict__ baseP, const bf16* __restrict__ gin,
    const bf16* __restrict__ S, const int* __restrict__ fromP,
    const int* __restrict__ backP, const bf16* __restrict__ BT,
    bf16* __restrict__ gout, int fused)
{
    __shared__ bf16 Bsw[128 * 128];   // 32 KB
    int tid = threadIdx.x;

    // stage B, destination-consecutive (bank-conflict-free LDS writes)
    #pragma unroll
    for (int t = 0; t < 8; t++) {
        int c = tid + t * 256;            // dst chunk id 0..2047
        int cmr = c & 15;
        int cq  = (c >> 4) & 3;
        int ckt = (c >> 6) & 3;
        int cn  = c >> 8;
        int brow = cn * 16 + cmr;
        int bcol = ckt * 32 + cq * 8;
        *(bf16x8*)&Bsw[(size_t)c * 8] =
            *(const bf16x8*)(BT + (size_t)brow * 128 + bcol);
    }
    __syncthreads();

    int wave = tid >> 6, lane = tid & 63;
    int quad = lane >> 4, mr = lane & 15;

    #pragma unroll 1
    for (int it = 0; it < 4; ++it) {
        int i0 = blockIdx.x * 256 + wave * 64 + it * 16;
        if (i0 >= N_EDGES) break;         // tail block (full 16-groups only)
        int i = i0 + mr;

        // ---- build this lane's 4 A-fragments in registers ----
        bf16x8 afr[4];
        if (!fused) {
            #pragma unroll
            for (int kt = 0; kt < 4; kt++) {
                bf16x8 bb = *(const bf16x8*)(baseP + (size_t)i * 128 + kt * 32 + quad * 8);
                #pragma unroll
                for (int j = 0; j < 8; j++)
                    afr[kt][j] = (bf16)fmaxf((float)bb[j], 0.f);
            }
        } else {
            const bf16* sr = S   + (size_t)fromP[i] * 128;
            const bf16* gr = gin + (size_t)backP[i] * 128;
            #pragma unroll
            for (int kt = 0; kt < 4; kt++) {
                int c = kt * 32 + quad * 8;
                bf16x8 bb = *(const bf16x8*)(baseP + (size_t)i * 128 + c);
                bf16x8 gg = *(const bf16x8*)(gr + c);
                bf16x8 ss = *(const bf16x8*)(sr + c);
                #pragma unroll
                for (int j = 0; j < 8; j++) {
                    float v = (float)bb[j] + (float)ss[j] - (float)gg[j];
                    afr[kt][j] = (bf16)fmaxf(v, 0.f);
                }
            }
        }

        // ---- MFMA: 8 col-tiles x 4 k-chunks ----
        f32x4 acc[8];
        #pragma unroll
        for (int n = 0; n < 8; n++) acc[n] = (f32x4){0.f, 0.f, 0.f, 0.f};
        #pragma unroll
        for (int kt = 0; kt < 4; kt++) {
            #pragma unroll
            for (int n = 0; n < 8; n++) {
                bf16x8 b = *(const bf16x8*)&Bsw[(size_t)(((n * 4 + kt) * 64) + lane) * 8];
                acc[n] = __builtin_amdgcn_mfma_f32_16x16x32_bf16(afr[kt], b, acc[n], 0, 0, 0);
            }
        }

        // ---- epilogue: C/D layout col=mr, row=quad*4+reg; pack bf16x2 via
        // lane-pair shfl -> 4B stores, 64B segments ----
        #pragma unroll
        for (int np = 0; np < 4; np++) {
            int n0 = np * 2;
            #pragma unroll
            for (int reg = 0; reg < 4; reg++) {
                float v0 = acc[n0][reg], v1 = acc[n0 + 1][reg];
                float o0 = __shfl_xor(v0, 1);
                float o1 = __shfl_xor(v1, 1);
                bf16x2 pk;
                int colb;
                if ((mr & 1) == 0) {
                    pk[0] = (bf16)v0; pk[1] = (bf16)o0;
                    colb = n0 * 16 + mr;
                } else {
                    pk[0] = (bf16)o1; pk[1] = (bf16)v1;
                    colb = (n0 + 1) * 16 + (mr ^ 1);
                }
                int row = i0 + quad * 4 + reg;
                *(bf16x2*)(gout + (size_t)row * 128 + colb) = pk;
            }
        }
    }
}

// ---------------------------------------------------------------------------
// Streaming segment sum: S[n,:] = bf16( sum_{i=off[n]}^{off[n+1]} g[i,:] )
__global__ __launch_bounds__(256) void segsum_stream(
    const bf16* __restrict__ g, const int* __restrict__ off, bf16* __restrict__ S)
{
    int n = blockIdx.x * 4 + (threadIdx.x >> 6);
    if (n >= N_NODES) return;
    int lane = threadIdx.x & 63;
    int o0 = off[n], o1 = off[n + 1];
    float a0 = 0.f, a1 = 0.f;
    for (int i = o0; i < o1; ++i) {
        bf16x2 v = *(const bf16x2*)(g + (size_t)i * 128 + lane * 2);
        a0 += (float)v[0];
        a1 += (float)v[1];
    }
    bf16x2 o; o[0] = (bf16)a0; o[1] = (bf16)a1;
    *(bf16x2*)(S + (size_t)n * 128 + lane * 2) = o;
}

// to-side readout: agg[n,:] = fp32 sum_{i in bucket n} g[backP[i],:]
__global__ __launch_bounds__(256) void segsum_final(
    const bf16* __restrict__ g, const int* __restrict__ off,
    const int* __restrict__ backP, float* __restrict__ agg)
{
    int n = blockIdx.x * 4 + (threadIdx.x >> 6);
    if (n >= N_NODES) return;
    int lane = threadIdx.x & 63;
    int o0 = off[n], o1 = off[n + 1];
    float a0 = 0.f, a1 = 0.f;
    for (int i = o0; i < o1; ++i) {
        int e = backP[i];
        bf16x2 v = *(const bf16x2*)(g + (size_t)e * 128 + lane * 2);
        a0 += (float)v[0];
        a1 += (float)v[1];
    }
    *(float2*)(agg + (size_t)n * 128 + lane * 2) = make_float2(a0, a1);
}

// ---------------------------------------------------------------------------
// out[n,:] = relu(U1x[n,:] + agg[n,:] + deg[n] * U2_b[:])
__global__ __launch_bounds__(256) void final_out(
    const float* __restrict__ U1x, const float* __restrict__ agg,
    const int* __restrict__ deg, const float* __restrict__ U2b,
    float* __restrict__ out)
{
    int gid = blockIdx.x * 256 + threadIdx.x;
    int n  = gid >> 5;
    if (n >= N_NODES) return;
    int c4 = gid & 31;
    float d = (float)deg[n];
    float4 a  = *(const float4*)(U1x + (size_t)n * 128 + c4 * 4);
    float4 ag = *(const float4*)(agg + (size_t)n * 128 + c4 * 4);
    float4 ub = *(const float4*)(U2b + c4 * 4);
    float4 r;
    r.x = fmaxf(a.x + ag.x + d * ub.x, 0.f);
    r.y = fmaxf(a.y + ag.y + d * ub.y, 0.f);
    r.z = fmaxf(a.z + ag.z + d * ub.z, 0.f);
    r.w = fmaxf(a.w + ag.w + d * ub.w, 0.f);
    *(float4*)(out + (size_t)n * 128 + c4 * 4) = r;
}

// ---------------------------------------------------------------------------
extern "C" void kernel_launch(void* const* d_in, const int* in_sizes, int n_in,
                              void* d_out, int out_size, void* d_ws, size_t ws_size,
                              hipStream_t stream) {
    const float* nf  = (const float*)d_in[0];
    const float* ef  = (const float*)d_in[1];
    // d_in[2] edge_hiddens: zeros -> h1 = relu(base); first GEMM uses fused=0
    const int* edges = (const int*)d_in[3];
    const int* from  = edges;
    const float* W1w = (const float*)d_in[4];
    const float* W1b = (const float*)d_in[5];
    const float* W2w = (const float*)d_in[6];
    const float* W2b = (const float*)d_in[7];
    const float* W3w = (const float*)d_in[8];
    const float* W3b = (const float*)d_in[9];
    const float* U1w = (const float*)d_in[10];
    const float* U1b = (const float*)d_in[11];
    const float* U2w = (const float*)d_in[12];
    const float* U2b = (const float*)d_in[13];
    float* out = (float*)d_out;

    const size_t NODE_MAT = (size_t)N_NODES * 128;
    const size_t EDGE_MAT = (size_t)N_EDGES * 128;
    char* w = (char*)d_ws;
    float* nodeW1 = (float*)w; w += NODE_MAT * 4;        // reused as U1x
    float* agg    = (float*)w; w += NODE_MAT * 4;
    bf16*  S      = (bf16*)w;  w += NODE_MAT * 2;
    bf16*  baseP  = (bf16*)w;  w += EDGE_MAT * 2;
    bf16*  g0     = (bf16*)w;  w += EDGE_MAT * 2;
    bf16*  g1     = (bf16*)w;  w += EDGE_MAT * 2;
    bf16*  W3T    = (bf16*)w;  w += 128 * 128 * 2;
    bf16*  U2T    = (bf16*)w;  w += 128 * 128 * 2;
    int*   deg    = (int*)w;   w += (size_t)N_NODES * 4;
    int*   off    = (int*)w;   w += (size_t)(N_NODES + 1) * 4;
    int*   cursor = (int*)w;   w += (size_t)N_NODES * 4;
    int*   bsum   = (int*)w;   w += (size_t)SCAN_BLOCKS * 4;
    int*   bpref  = (int*)w;   w += (size_t)SCAN_BLOCKS * 4;
    int*   se     = (int*)w;   w += (size_t)N_EDGES * 4;
    int*   rank   = (int*)w;   w += (size_t)N_EDGES * 4;
    int*   fromP  = (int*)w;   w += (size_t)N_EDGES * 4;
    int*   backP  = (int*)w;   w += (size_t)N_EDGES * 4;

    // ---- CSR build + sorted-space maps ----
    hipMemsetAsync(deg, 0, (size_t)N_NODES * 4, stream);
    deg_hist<<<(N_EDGES + 255) / 256, 256, 0, stream>>>(from, deg, N_EDGES);
    block_sums<<<SCAN_BLOCKS, 256, 0, stream>>>(deg, bsum);
    scan_partials<<<1, 256, 0, stream>>>(bsum, bpref, off);
    block_scan<<<SCAN_BLOCKS, 256, 0, stream>>>(deg, bpref, off, cursor);
    scatter_csr<<<(N_EDGES + 255) / 256, 256, 0, stream>>>(from, cursor, se, rank, N_EDGES);
    make_maps<<<(N_EDGES + 255) / 256, 256, 0, stream>>>(se, from, rank, fromP, backP, N_EDGES);

    // ---- loop-invariant precompute ----
    prep_weights<<<(128 * 128 + 255) / 256, 256, 0, stream>>>(W3w, U2w, W3T, U2T);
    node_gemm<<<(N_NODES + 63) / 64, 256, 0, stream>>>(nf, W1w, W1b, nodeW1, N_NODES);
    base_sorted<<<(N_EDGES + 511) / 512, 256, 0, stream>>>(
        nodeW1, fromP, se, ef, W2w, W2b, W3b, baseP);

    // ---- message passing (sorted space, ping-pong g) ----
    const int EGRID = (N_EDGES + 255) / 256;   // 2344
    bf16* G[2] = {g0, g1};
    edge_mfma_v2<<<EGRID, 256, 0, stream>>>(
        baseP, G[0], S, fromP, backP, W3T, G[0], 0);
    segsum_stream<<<(N_NODES + 3) / 4, 256, 0, stream>>>(G[0], off, S);
    int cur = 0;
    for (int it = 1; it < 5; ++it) {
        edge_mfma_v2<<<EGRID, 256, 0, stream>>>(
            baseP, G[cur], S, fromP, backP, W3T, G[cur ^ 1], 1);
        cur ^= 1;
        segsum_stream<<<(N_NODES + 3) / 4, 256, 0, stream>>>(G[cur], off, S);
    }
    // ---- readout: h6 built in-flight, B = U2T; then to-side segment sum ----
    edge_mfma_v2<<<EGRID, 256, 0, stream>>>(
        baseP, G[cur], S, fromP, backP, U2T, G[cur ^ 1], 1);
    cur ^= 1;
    segsum_final<<<(N_NODES + 3) / 4, 256, 0, stream>>>(G[cur], off, backP, agg);

    node_gemm<<<(N_NODES + 63) / 64, 256, 0, stream>>>(nf, U1w, U1b, nodeW1, N_NODES);
    final_out<<<(N_NODES * 32 + 255) / 256, 256, 0, stream>>>(nodeW1, agg, deg, U2b, out);
}